// Round 1
// baseline (204.214 us; speedup 1.0000x reference)
//
#include <hip/hip_runtime.h>
#include <stdint.h>

#define DEVI __device__ __forceinline__

typedef unsigned short u16;
typedef __attribute__((ext_vector_type(4))) float f32x4;
typedef __attribute__((ext_vector_type(8))) short bf16x8;

constexpr int T_LEN = 2048;
constexpr int BSZ   = 2;
constexpr int DM    = 1024;
constexpr int NH    = 16;
constexpr int HD    = 64;
constexpr int MROWS = T_LEN * BSZ;   // 4096
constexpr float LORA_S = 16.0f / 16.0f;  // SCALE / RANK

DEVI u16 f2bf(float x) {
  union { float f; uint32_t u; } v; v.f = x;
  uint32_t r = (v.u + 0x7FFFu + ((v.u >> 16) & 1u)) >> 16;  // RNE
  return (u16)r;
}

DEVI void gload_lds16(const void* g, void* l) {
  __builtin_amdgcn_global_load_lds(
      (const __attribute__((address_space(1))) void*)g,
      (__attribute__((address_space(3))) void*)l, 16, 0, 0);
}

DEVI f32x4 mfma16(bf16x8 a, bf16x8 b, f32x4 c) {
  return __builtin_amdgcn_mfma_f32_16x16x32_bf16(a, b, c, 0, 0, 0);
}

// XOR-swizzled u16 index into a [rows][64]-u16 LDS tile (16B-granular, T2/G4)
DEVI int swz16(int row, int c8) { return row * 64 + ((c8 ^ (row & 7)) << 3); }

// ---------------- prep: fold LoRA into Wk/Wv, cast weights + query to bf16 --
__global__ void prep_kernel(const float* __restrict__ query,
                            const float* __restrict__ W,
                            const float* __restrict__ ka, const float* __restrict__ kb,
                            const float* __restrict__ va, const float* __restrict__ vb,
                            const float* __restrict__ ow,
                            u16* __restrict__ Wm, u16* __restrict__ Wo,
                            u16* __restrict__ Aq) {
  const int W3 = 3 * DM * DM;
  const int WO = DM * DM;
  const int AQ = MROWS * DM;
  const int total = W3 + WO + AQ;
  for (int idx = blockIdx.x * blockDim.x + threadIdx.x; idx < total;
       idx += gridDim.x * blockDim.x) {
    if (idx < W3) {
      const int n = idx >> 10, k = idx & 1023;
      float w = W[idx];
      if (n >= 2 * DM) {
        const int n2 = n - 2 * DM;
        float a = 0.f;
#pragma unroll
        for (int r = 0; r < 16; ++r) a += va[r * DM + k] * vb[r * DM + n2];
        w += LORA_S * a;
      } else if (n >= DM) {
        const int n2 = n - DM;
        float a = 0.f;
#pragma unroll
        for (int r = 0; r < 16; ++r) a += ka[r * DM + k] * kb[r * DM + n2];
        w += LORA_S * a;
      }
      Wm[idx] = f2bf(w);
    } else if (idx < W3 + WO) {
      const int i = idx - W3;
      Wo[i] = f2bf(ow[i]);
    } else {
      const int i = idx - W3 - WO;
      Aq[i] = f2bf(query[i]);
    }
  }
}

// ---------------- GEMM: C[m][n] = sum_k A[m][k]*Bt[n][k] + bias[n] ----------
// EPIL 0: scatter q/k/v (q scaled 1/8, v transposed per head). EPIL 1: fp32 C.
template <int EPIL>
__global__ __launch_bounds__(256) void gemm_bt(
    const u16* __restrict__ A, const u16* __restrict__ Bt,
    const float* __restrict__ bias, float* __restrict__ Cf,
    u16* __restrict__ Qb, u16* __restrict__ Kb, u16* __restrict__ Vt,
    int M, int N, int K) {
  constexpr int BM = 128, BN = 128, BK = 64;
  __shared__ alignas(16) u16 Al[BM * BK];
  __shared__ alignas(16) u16 Bl[BN * BK];
  const int tid = threadIdx.x;
  const int wv = tid >> 6, ln = tid & 63;
  const int l16 = ln & 15, lhi = ln >> 4;
  const int row0 = blockIdx.x * BM, col0 = blockIdx.y * BN;
  const int wr = (wv >> 1) * 64, wc = (wv & 1) * 64;

  f32x4 acc[4][4];
#pragma unroll
  for (int i = 0; i < 4; ++i)
#pragma unroll
    for (int j = 0; j < 4; ++j) acc[i][j] = f32x4{0.f, 0.f, 0.f, 0.f};

  // staging: lane -> linear LDS slot (row=ln>>3, group=ln&7); global source
  // group pre-swizzled so swizzled reads get logical data (m201 pattern)
  const int srow = ln >> 3;
  const int scol = (((ln & 7) ^ (ln >> 3)) & 7) * 8;

  for (int k0 = 0; k0 < K; k0 += BK) {
    __syncthreads();
#pragma unroll
    for (int it = 0; it < 4; ++it) {
      const int c = wv * 4 + it;  // 0..15, 8 rows each
      gload_lds16(A + (size_t)(row0 + c * 8 + srow) * K + k0 + scol, &Al[c * 512]);
      gload_lds16(Bt + (size_t)(col0 + c * 8 + srow) * K + k0 + scol, &Bl[c * 512]);
    }
    __syncthreads();
#pragma unroll
    for (int ks = 0; ks < 2; ++ks) {
      bf16x8 af[4], bfr[4];
#pragma unroll
      for (int m = 0; m < 4; ++m)
        af[m] = *(const bf16x8*)&Al[swz16(wr + m * 16 + l16, ks * 4 + lhi)];
#pragma unroll
      for (int n = 0; n < 4; ++n)
        bfr[n] = *(const bf16x8*)&Bl[swz16(wc + n * 16 + l16, ks * 4 + lhi)];
#pragma unroll
      for (int m = 0; m < 4; ++m)
#pragma unroll
        for (int n = 0; n < 4; ++n) acc[m][n] = mfma16(af[m], bfr[n], acc[m][n]);
    }
  }

#pragma unroll
  for (int m = 0; m < 4; ++m) {
#pragma unroll
    for (int n = 0; n < 4; ++n) {
      const int col = col0 + wc + n * 16 + l16;
      const float bc = bias[col];
#pragma unroll
      for (int r = 0; r < 4; ++r) {
        const int row = row0 + wr + m * 16 + lhi * 4 + r;
        const float v = acc[m][n][r] + bc;
        if constexpr (EPIL == 0) {
          const int t = row >> 1, b = row & 1;  // row = t*BSZ + b
          if (col < DM) {
            const int h = col >> 6, dd = col & 63;
            Qb[(((size_t)(b * NH + h)) * T_LEN + t) * HD + dd] = f2bf(v * 0.125f);
          } else if (col < 2 * DM) {
            const int c2 = col - DM, h = c2 >> 6, dd = c2 & 63;
            Kb[(((size_t)(b * NH + h)) * T_LEN + t) * HD + dd] = f2bf(v);
          } else {
            const int c2 = col - 2 * DM, h = c2 >> 6, dd = c2 & 63;
            Vt[(((size_t)(b * NH + h)) * HD + dd) * T_LEN + t] = f2bf(v);
          }
        } else {
          Cf[(size_t)row * N + col] = v;
        }
      }
    }
  }
}

// ---------------- flash attention: 4 waves x 32 q-rows, KV tiles of 64 ------
__global__ __launch_bounds__(256) void attn_kernel(const u16* __restrict__ Qb,
                                                   const u16* __restrict__ Kb,
                                                   const u16* __restrict__ Vt,
                                                   u16* __restrict__ Ob) {
  constexpr int KBLK = 64;
  constexpr int NT = T_LEN / KBLK;  // 32
  __shared__ alignas(16) u16 Kl[2][KBLK * HD];
  __shared__ alignas(16) u16 Vl[2][HD * KBLK];
  __shared__ alignas(16) u16 Pl[4][32 * KBLK];

  const int tid = threadIdx.x;
  const int wv = tid >> 6, ln = tid & 63;
  const int l16 = ln & 15, lhi = ln >> 4;
  const int bh = blockIdx.y;
  const int b = bh >> 4, h = bh & 15;
  const int q0 = blockIdx.x * 128 + wv * 32;

  const u16* Qh = Qb + (size_t)bh * T_LEN * HD;
  const u16* Kh = Kb + (size_t)bh * T_LEN * HD;
  const u16* Vh = Vt + (size_t)bh * HD * T_LEN;

  // Q fragments in registers (already pre-scaled by 1/8)
  bf16x8 qf[2][2];
#pragma unroll
  for (int m = 0; m < 2; ++m)
#pragma unroll
    for (int ks = 0; ks < 2; ++ks)
      qf[m][ks] = *(const bf16x8*)&Qh[(size_t)(q0 + m * 16 + l16) * HD + ks * 32 + lhi * 8];

  f32x4 o[2][4];
  float mi[2][4], li[2][4];
#pragma unroll
  for (int m = 0; m < 2; ++m)
#pragma unroll
    for (int n = 0; n < 4; ++n) o[m][n] = f32x4{0.f, 0.f, 0.f, 0.f};
#pragma unroll
  for (int m = 0; m < 2; ++m)
#pragma unroll
    for (int r = 0; r < 4; ++r) { mi[m][r] = -1e30f; li[m][r] = 0.f; }

  const int srow = ln >> 3;
  const int scol = (((ln & 7) ^ (ln >> 3)) & 7) * 8;

  auto stage = [&](int buf, int kt) {
    const int kt0 = kt * KBLK;
#pragma unroll
    for (int it = 0; it < 2; ++it) {
      const int c = wv * 2 + it;  // 0..7
      gload_lds16(Kh + (size_t)(kt0 + c * 8 + srow) * HD + scol, &Kl[buf][c * 512]);
      gload_lds16(Vh + (size_t)(c * 8 + srow) * T_LEN + kt0 + scol, &Vl[buf][c * 512]);
    }
  };

  stage(0, 0);
  __syncthreads();
  int cur = 0;
  for (int kt = 0; kt < NT; ++kt) {
    if (kt + 1 < NT) stage(cur ^ 1, kt + 1);

    // S = Q K^T   (S[q][key], 32x64 per wave)
    f32x4 s[2][4];
#pragma unroll
    for (int m = 0; m < 2; ++m)
#pragma unroll
      for (int n = 0; n < 4; ++n) s[m][n] = f32x4{0.f, 0.f, 0.f, 0.f};
#pragma unroll
    for (int ks = 0; ks < 2; ++ks) {
      bf16x8 kf[4];
#pragma unroll
      for (int n = 0; n < 4; ++n)
        kf[n] = *(const bf16x8*)&Kl[cur][swz16(n * 16 + l16, ks * 4 + lhi)];
#pragma unroll
      for (int m = 0; m < 2; ++m)
#pragma unroll
        for (int n = 0; n < 4; ++n) s[m][n] = mfma16(qf[m][ks], kf[n], s[m][n]);
    }

    // online softmax per q-row; row r_glob = m*16 + lhi*4 + r, cols n*16+l16
#pragma unroll
    for (int m = 0; m < 2; ++m) {
#pragma unroll
      for (int r = 0; r < 4; ++r) {
        float tm = fmaxf(fmaxf(s[m][0][r], s[m][1][r]), fmaxf(s[m][2][r], s[m][3][r]));
#pragma unroll
        for (int off = 1; off < 16; off <<= 1) tm = fmaxf(tm, __shfl_xor(tm, off));
        const float mo = mi[m][r];
        const float mn = fmaxf(mo, tm);
        const float alpha = __expf(mo - mn);
        float p[4], ts = 0.f;
#pragma unroll
        for (int n = 0; n < 4; ++n) { p[n] = __expf(s[m][n][r] - mn); ts += p[n]; }
#pragma unroll
        for (int off = 1; off < 16; off <<= 1) ts += __shfl_xor(ts, off);
        li[m][r] = li[m][r] * alpha + ts;
        mi[m][r] = mn;
#pragma unroll
        for (int n = 0; n < 4; ++n) o[m][n][r] *= alpha;
        const int prow = m * 16 + lhi * 4 + r;
#pragma unroll
        for (int n = 0; n < 4; ++n)
          Pl[wv][prow * 64 + ((n * 16 + l16) ^ ((prow & 7) << 3))] = f2bf(p[n]);
      }
    }

    // O += P V   (A = P 32x64-keys, B = V^T tile [dim][key])
#pragma unroll
    for (int ks = 0; ks < 2; ++ks) {
      bf16x8 pf[2], vf[4];
#pragma unroll
      for (int m = 0; m < 2; ++m)
        pf[m] = *(const bf16x8*)&Pl[wv][swz16(m * 16 + l16, ks * 4 + lhi)];
#pragma unroll
      for (int n = 0; n < 4; ++n)
        vf[n] = *(const bf16x8*)&Vl[cur][swz16(n * 16 + l16, ks * 4 + lhi)];
#pragma unroll
      for (int m = 0; m < 2; ++m)
#pragma unroll
        for (int n = 0; n < 4; ++n) o[m][n] = mfma16(pf[m], vf[n], o[m][n]);
    }
    __syncthreads();
    cur ^= 1;
  }

  // epilogue: O/l -> Ob[(t*BSZ+b)*DM + h*64 + dim] (bf16)
#pragma unroll
  for (int m = 0; m < 2; ++m) {
#pragma unroll
    for (int r = 0; r < 4; ++r) {
      const float inv = 1.0f / li[m][r];
      const int trow = q0 + m * 16 + lhi * 4 + r;
#pragma unroll
      for (int n = 0; n < 4; ++n) {
        const float val = o[m][n][r] * inv;
        Ob[((size_t)trow * BSZ + b) * DM + h * HD + n * 16 + l16] = f2bf(val);
      }
    }
  }
}

// ---------------- launcher --------------------------------------------------
extern "C" void kernel_launch(void* const* d_in, const int* in_sizes, int n_in,
                              void* d_out, int out_size, void* d_ws, size_t ws_size,
                              hipStream_t stream) {
  const float* query = (const float*)d_in[0];
  const float* W     = (const float*)d_in[5];
  const float* bias  = (const float*)d_in[6];
  const float* ow    = (const float*)d_in[7];
  const float* ob    = (const float*)d_in[8];
  const float* ka    = (const float*)d_in[9];
  const float* kb    = (const float*)d_in[10];
  const float* va    = (const float*)d_in[11];
  const float* vb    = (const float*)d_in[12];

  char* ws = (char*)d_ws;
  u16* Wm = (u16*)ws; ws += (size_t)3 * DM * DM * 2;       // 6 MB
  u16* Wo = (u16*)ws; ws += (size_t)DM * DM * 2;           // 2 MB
  u16* Aq = (u16*)ws; ws += (size_t)MROWS * DM * 2;        // 8 MB
  u16* Qb = (u16*)ws; ws += (size_t)BSZ * NH * T_LEN * HD * 2;  // 8 MB
  u16* Kb = (u16*)ws; ws += (size_t)BSZ * NH * T_LEN * HD * 2;  // 8 MB
  u16* Vt = (u16*)ws; ws += (size_t)BSZ * NH * T_LEN * HD * 2;  // 8 MB
  u16* Ob = (u16*)ws; ws += (size_t)MROWS * DM * 2;        // 8 MB

  prep_kernel<<<2048, 256, 0, stream>>>(query, W, ka, kb, va, vb, ow, Wm, Wo, Aq);

  gemm_bt<0><<<dim3(MROWS / 128, (3 * DM) / 128), 256, 0, stream>>>(
      Aq, Wm, bias, nullptr, Qb, Kb, Vt, MROWS, 3 * DM, DM);

  attn_kernel<<<dim3(T_LEN / 128, BSZ * NH), 256, 0, stream>>>(Qb, Kb, Vt, Ob);

  gemm_bt<1><<<dim3(MROWS / 128, DM / 128), 256, 0, stream>>>(
      Ob, Wo, ob, (float*)d_out, nullptr, nullptr, nullptr, MROWS, DM, DM);
}

// Round 3
// 162.576 us; speedup vs baseline: 1.2561x; 1.2561x over previous
//
#include <hip/hip_runtime.h>
#include <stdint.h>

#define DEVI __device__ __forceinline__

typedef unsigned short u16;
typedef __attribute__((ext_vector_type(4))) float f32x4;
typedef __attribute__((ext_vector_type(16))) float f32x16;
typedef __attribute__((ext_vector_type(8))) short bf16x8;
typedef __attribute__((ext_vector_type(2))) unsigned int u32x2;

constexpr int T_LEN = 2048;
constexpr int BSZ   = 2;
constexpr int DM    = 1024;
constexpr int NH    = 16;
constexpr int HD    = 64;
constexpr int MROWS = T_LEN * BSZ;   // 4096
constexpr float LORA_S = 16.0f / 16.0f;  // SCALE / RANK
// Q pre-scale: 1/sqrt(64) * log2(e)  -> scores land in exp2 domain
constexpr float QSCALE = 0.125f * 1.4426950408889634f;

DEVI u16 f2bf(float x) {
  union { float f; uint32_t u; } v; v.f = x;
  uint32_t r = (v.u + 0x7FFFu + ((v.u >> 16) & 1u)) >> 16;  // RNE
  return (u16)r;
}

DEVI uint32_t pk2bf(float a, float b) {  // low = a, high = b (RNE)
  return (uint32_t)f2bf(a) | ((uint32_t)f2bf(b) << 16);
}

DEVI void gload_lds16(const void* g, void* l) {
  __builtin_amdgcn_global_load_lds(
      (const __attribute__((address_space(1))) void*)g,
      (__attribute__((address_space(3))) void*)l, 16, 0, 0);
}

DEVI f32x4 mfma16(bf16x8 a, bf16x8 b, f32x4 c) {
  return __builtin_amdgcn_mfma_f32_16x16x32_bf16(a, b, c, 0, 0, 0);
}
DEVI f32x16 mfma32(bf16x8 a, bf16x8 b, f32x16 c) {
  return __builtin_amdgcn_mfma_f32_32x32x16_bf16(a, b, c, 0, 0, 0);
}

// XOR-swizzled u16 index into a [rows][64]-u16 LDS tile (16B-granular, T2/G4)
DEVI int swz16(int row, int c8) { return row * 64 + ((c8 ^ (row & 7)) << 3); }

// ---------------- prep: fold LoRA into Wk/Wv, cast weights + query to bf16 --
__global__ void prep_kernel(const float* __restrict__ query,
                            const float* __restrict__ W,
                            const float* __restrict__ ka, const float* __restrict__ kb,
                            const float* __restrict__ va, const float* __restrict__ vb,
                            const float* __restrict__ ow,
                            u16* __restrict__ Wm, u16* __restrict__ Wo,
                            u16* __restrict__ Aq) {
  const int W3 = 3 * DM * DM;
  const int WO = DM * DM;
  const int AQ = MROWS * DM;
  const int total = W3 + WO + AQ;
  for (int idx = blockIdx.x * blockDim.x + threadIdx.x; idx < total;
       idx += gridDim.x * blockDim.x) {
    if (idx < W3) {
      const int n = idx >> 10, k = idx & 1023;
      float w = W[idx];
      if (n >= 2 * DM) {
        const int n2 = n - 2 * DM;
        float a = 0.f;
#pragma unroll
        for (int r = 0; r < 16; ++r) a += va[r * DM + k] * vb[r * DM + n2];
        w += LORA_S * a;
      } else if (n >= DM) {
        const int n2 = n - DM;
        float a = 0.f;
#pragma unroll
        for (int r = 0; r < 16; ++r) a += ka[r * DM + k] * kb[r * DM + n2];
        w += LORA_S * a;
      }
      Wm[idx] = f2bf(w);
    } else if (idx < W3 + WO) {
      const int i = idx - W3;
      Wo[i] = f2bf(ow[i]);
    } else {
      const int i = idx - W3 - WO;
      Aq[i] = f2bf(query[i]);
    }
  }
}

// ---------------- GEMM: C[m][n] = sum_k A[m][k]*Bt[n][k] + bias[n] ----------
// EPIL 0: scatter q/k/v (q scaled QSCALE, v transposed per head). EPIL 1: fp32 C.
template <int EPIL>
__global__ __launch_bounds__(256) void gemm_bt(
    const u16* __restrict__ A, const u16* __restrict__ Bt,
    const float* __restrict__ bias, float* __restrict__ Cf,
    u16* __restrict__ Qb, u16* __restrict__ Kb, u16* __restrict__ Vt,
    int M, int N, int K) {
  constexpr int BM = 128, BN = 128, BK = 64;
  __shared__ alignas(16) u16 Al[BM * BK];
  __shared__ alignas(16) u16 Bl[BN * BK];
  const int tid = threadIdx.x;
  const int wv = tid >> 6, ln = tid & 63;
  const int l16 = ln & 15, lhi = ln >> 4;
  const int row0 = blockIdx.x * BM, col0 = blockIdx.y * BN;
  const int wr = (wv >> 1) * 64, wc = (wv & 1) * 64;

  f32x4 acc[4][4];
#pragma unroll
  for (int i = 0; i < 4; ++i)
#pragma unroll
    for (int j = 0; j < 4; ++j) acc[i][j] = f32x4{0.f, 0.f, 0.f, 0.f};

  const int srow = ln >> 3;
  const int scol = (((ln & 7) ^ (ln >> 3)) & 7) * 8;

  for (int k0 = 0; k0 < K; k0 += BK) {
    __syncthreads();
#pragma unroll
    for (int it = 0; it < 4; ++it) {
      const int c = wv * 4 + it;  // 0..15, 8 rows each
      gload_lds16(A + (size_t)(row0 + c * 8 + srow) * K + k0 + scol, &Al[c * 512]);
      gload_lds16(Bt + (size_t)(col0 + c * 8 + srow) * K + k0 + scol, &Bl[c * 512]);
    }
    __syncthreads();
#pragma unroll
    for (int ks = 0; ks < 2; ++ks) {
      bf16x8 af[4], bfr[4];
#pragma unroll
      for (int m = 0; m < 4; ++m)
        af[m] = *(const bf16x8*)&Al[swz16(wr + m * 16 + l16, ks * 4 + lhi)];
#pragma unroll
      for (int n = 0; n < 4; ++n)
        bfr[n] = *(const bf16x8*)&Bl[swz16(wc + n * 16 + l16, ks * 4 + lhi)];
#pragma unroll
      for (int m = 0; m < 4; ++m)
#pragma unroll
        for (int n = 0; n < 4; ++n) acc[m][n] = mfma16(af[m], bfr[n], acc[m][n]);
    }
  }

#pragma unroll
  for (int m = 0; m < 4; ++m) {
#pragma unroll
    for (int n = 0; n < 4; ++n) {
      const int col = col0 + wc + n * 16 + l16;
      const float bc = bias[col];
#pragma unroll
      for (int r = 0; r < 4; ++r) {
        const int row = row0 + wr + m * 16 + lhi * 4 + r;
        const float v = acc[m][n][r] + bc;
        if constexpr (EPIL == 0) {
          const int t = row >> 1, b = row & 1;  // row = t*BSZ + b
          if (col < DM) {
            const int h = col >> 6, dd = col & 63;
            Qb[(((size_t)(b * NH + h)) * T_LEN + t) * HD + dd] = f2bf(v * QSCALE);
          } else if (col < 2 * DM) {
            const int c2 = col - DM, h = c2 >> 6, dd = c2 & 63;
            Kb[(((size_t)(b * NH + h)) * T_LEN + t) * HD + dd] = f2bf(v);
          } else {
            const int c2 = col - 2 * DM, h = c2 >> 6, dd = c2 & 63;
            Vt[(((size_t)(b * NH + h)) * HD + dd) * T_LEN + t] = f2bf(v);
          }
        } else {
          Cf[(size_t)row * N + col] = v;
        }
      }
    }
  }
}

// ---------------- flash attention: swapped-QK^T, in-register softmax --------
// 4 waves x 32 q-rows; KV tiles of 64 double-buffered; 32x32x16 MFMA.
// Per wave: S^T = K*Q'^T (lane owns one q column), softmax in-register,
// P->bf16 via cvt_pk + permlane32_swap, O^T = V^T * P^T.
__global__ __launch_bounds__(256) void attn_kernel(const u16* __restrict__ Qb,
                                                   const u16* __restrict__ Kb,
                                                   const u16* __restrict__ Vt,
                                                   u16* __restrict__ Ob) {
  constexpr int KBLK = 64;
  constexpr int NT = T_LEN / KBLK;  // 32
  __shared__ alignas(16) u16 Kl[2][KBLK * HD];   // [key][d]
  __shared__ alignas(16) u16 Vl[2][HD * KBLK];   // [dim][key]

  const int tid = threadIdx.x;
  const int wv = tid >> 6, ln = tid & 63;
  const int l32 = ln & 31, hi = ln >> 5;
  const int bh = blockIdx.y;
  const int b = bh >> 4, h = bh & 15;
  const int q0 = blockIdx.x * 128 + wv * 32;  // t-index base of this wave

  const u16* Qh = Qb + (size_t)bh * T_LEN * HD;
  const u16* Kh = Kb + (size_t)bh * T_LEN * HD;
  const u16* Vh = Vt + (size_t)bh * HD * T_LEN;

  // Q B-fragments: row = q = l32, k = kd*16 + hi*8 + j  (pre-scaled by QSCALE)
  bf16x8 qf[4];
#pragma unroll
  for (int kd = 0; kd < 4; ++kd)
    qf[kd] = *(const bf16x8*)&Qh[(size_t)(q0 + l32) * HD + kd * 16 + hi * 8];

  f32x16 ot[2] = {f32x16{}, f32x16{}};  // O^T accumulators (dim tiles 0,1)
  float mi = -1e30f, li = 0.f;

  const int srow = ln >> 3;
  const int scol = (((ln & 7) ^ (ln >> 3)) & 7) * 8;

  auto stage = [&](int buf, int kt) {
    const int kt0 = kt * KBLK;
#pragma unroll
    for (int it = 0; it < 2; ++it) {
      const int c = wv * 2 + it;  // 0..7
      gload_lds16(Kh + (size_t)(kt0 + c * 8 + srow) * HD + scol, &Kl[buf][c * 512]);
      gload_lds16(Vh + (size_t)(c * 8 + srow) * T_LEN + kt0 + scol, &Vl[buf][c * 512]);
    }
  };

  stage(0, 0);
  __syncthreads();
  int cur = 0;
  for (int kt = 0; kt < NT; ++kt) {
    if (kt + 1 < NT) stage(cur ^ 1, kt + 1);

    // S^T[key][q]: st[mk], key = mk*32 + (r&3) + 8*(r>>2) + 4*hi, q col = l32
    f32x16 st[2] = {f32x16{}, f32x16{}};
#pragma unroll
    for (int kd = 0; kd < 4; ++kd) {
      bf16x8 k0 = *(const bf16x8*)&Kl[cur][swz16(l32, kd * 2 + hi)];
      bf16x8 k1 = *(const bf16x8*)&Kl[cur][swz16(32 + l32, kd * 2 + hi)];
      st[0] = mfma32(k0, qf[kd], st[0]);
      st[1] = mfma32(k1, qf[kd], st[1]);
    }

    // tile max for this q column (in-lane 32 values + partner lane)
    float tm = st[0][0];
#pragma unroll
    for (int r = 1; r < 16; ++r) tm = fmaxf(tm, st[0][r]);
#pragma unroll
    for (int r = 0; r < 16; ++r) tm = fmaxf(tm, st[1][r]);
    tm = fmaxf(tm, __shfl_xor(tm, 32));

    // defer-max (T13, THR=8 in exp2 domain): rescale only on real growth
    if (!__all(tm <= mi + 8.0f)) {
      const float mn = fmaxf(mi, tm);
      const float al = __builtin_amdgcn_exp2f(mi - mn);
      li *= al;
#pragma unroll
      for (int dt = 0; dt < 2; ++dt)
#pragma unroll
        for (int r = 0; r < 16; ++r) ot[dt][r] *= al;
      mi = mn;
    }

    // P = exp2(S^T - mi), packed to bf16 pairs; row-sum accumulated
    float ts = 0.f;
    uint32_t c[2][8];
#pragma unroll
    for (int mk = 0; mk < 2; ++mk)
#pragma unroll
      for (int d = 0; d < 8; ++d) {
        const float pa = __builtin_amdgcn_exp2f(st[mk][2 * d] - mi);
        const float pb = __builtin_amdgcn_exp2f(st[mk][2 * d + 1] - mi);
        ts += pa + pb;
        c[mk][d] = pk2bf(pa, pb);
      }
    ts += __shfl_xor(ts, 32);
    li += ts;

    // O^T += V^T P^T : redistribute P quads via permlane32_swap -> B-frags
#pragma unroll
    for (int ksl = 0; ksl < 4; ++ksl) {
      const int mk = ksl >> 1, s2 = ksl & 1;
      uint32_t a0 = c[mk][4 * s2 + 0], b0 = c[mk][4 * s2 + 2];
      uint32_t a1 = c[mk][4 * s2 + 1], b1 = c[mk][4 * s2 + 3];
      u32x2 r0 = __builtin_amdgcn_permlane32_swap(a0, b0, false, false);
      u32x2 r1 = __builtin_amdgcn_permlane32_swap(a1, b1, false, false);
      union { bf16x8 v; uint32_t u[4]; } pu;
      pu.u[0] = r0[0]; pu.u[1] = r1[0]; pu.u[2] = r0[1]; pu.u[3] = r1[1];
      bf16x8 vf0 = *(const bf16x8*)&Vl[cur][swz16(l32, ksl * 2 + hi)];
      bf16x8 vf1 = *(const bf16x8*)&Vl[cur][swz16(32 + l32, ksl * 2 + hi)];
      ot[0] = mfma32(vf0, pu.v, ot[0]);
      ot[1] = mfma32(vf1, pu.v, ot[1]);
    }
    __syncthreads();
    cur ^= 1;
  }

  // epilogue: O^T[dim][q]/li -> Ob[(t*BSZ+b)*DM + h*64 + dim], 4-dim packed
  const float inv = 1.0f / li;
  const size_t rowbase = ((size_t)(q0 + l32) * BSZ + b) * DM + h * HD;
#pragma unroll
  for (int dt = 0; dt < 2; ++dt) {
#pragma unroll
    for (int g = 0; g < 4; ++g) {
      const float v0 = ot[dt][4 * g + 0] * inv;
      const float v1 = ot[dt][4 * g + 1] * inv;
      const float v2 = ot[dt][4 * g + 2] * inv;
      const float v3 = ot[dt][4 * g + 3] * inv;
      u32x2 w; w[0] = pk2bf(v0, v1); w[1] = pk2bf(v2, v3);
      const int dim = dt * 32 + 8 * g + 4 * hi;
      *(u32x2*)&Ob[rowbase + dim] = w;
    }
  }
}

// ---------------- launcher --------------------------------------------------
extern "C" void kernel_launch(void* const* d_in, const int* in_sizes, int n_in,
                              void* d_out, int out_size, void* d_ws, size_t ws_size,
                              hipStream_t stream) {
  const float* query = (const float*)d_in[0];
  const float* W     = (const float*)d_in[5];
  const float* bias  = (const float*)d_in[6];
  const float* ow    = (const float*)d_in[7];
  const float* ob    = (const float*)d_in[8];
  const float* ka    = (const float*)d_in[9];
  const float* kb    = (const float*)d_in[10];
  const float* va    = (const float*)d_in[11];
  const float* vb    = (const float*)d_in[12];

  char* ws = (char*)d_ws;
  u16* Wm = (u16*)ws; ws += (size_t)3 * DM * DM * 2;       // 6 MB
  u16* Wo = (u16*)ws; ws += (size_t)DM * DM * 2;           // 2 MB
  u16* Aq = (u16*)ws; ws += (size_t)MROWS * DM * 2;        // 8 MB
  u16* Qb = (u16*)ws; ws += (size_t)BSZ * NH * T_LEN * HD * 2;  // 8 MB
  u16* Kb = (u16*)ws; ws += (size_t)BSZ * NH * T_LEN * HD * 2;  // 8 MB
  u16* Vt = (u16*)ws; ws += (size_t)BSZ * NH * T_LEN * HD * 2;  // 8 MB
  u16* Ob = (u16*)ws; ws += (size_t)MROWS * DM * 2;        // 8 MB

  prep_kernel<<<2048, 256, 0, stream>>>(query, W, ka, kb, va, vb, ow, Wm, Wo, Aq);

  gemm_bt<0><<<dim3(MROWS / 128, (3 * DM) / 128), 256, 0, stream>>>(
      Aq, Wm, bias, nullptr, Qb, Kb, Vt, MROWS, 3 * DM, DM);

  attn_kernel<<<dim3(T_LEN / 128, BSZ * NH), 256, 0, stream>>>(Qb, Kb, Vt, Ob);

  gemm_bt<1><<<dim3(MROWS / 128, DM / 128), 256, 0, stream>>>(
      Ob, Wo, ob, (float*)d_out, nullptr, nullptr, nullptr, MROWS, DM, DM);
}

// Round 4
// 138.167 us; speedup vs baseline: 1.4780x; 1.1767x over previous
//
#include <hip/hip_runtime.h>
#include <stdint.h>

#define DEVI __device__ __forceinline__

typedef unsigned short u16;
typedef __attribute__((ext_vector_type(4))) float f32x4;
typedef __attribute__((ext_vector_type(16))) float f32x16;
typedef __attribute__((ext_vector_type(8))) short bf16x8;
typedef __attribute__((ext_vector_type(2))) unsigned int u32x2;

constexpr int T_LEN = 2048;
constexpr int BSZ   = 2;
constexpr int DM    = 1024;
constexpr int NH    = 16;
constexpr int HD    = 64;
constexpr int MROWS = T_LEN * BSZ;   // 4096
constexpr float LORA_S = 16.0f / 16.0f;  // SCALE / RANK
// Q pre-scale: 1/sqrt(64) * log2(e)  -> scores land in exp2 domain
constexpr float QSCALE = 0.125f * 1.4426950408889634f;

DEVI u16 f2bf(float x) {
  union { float f; uint32_t u; } v; v.f = x;
  uint32_t r = (v.u + 0x7FFFu + ((v.u >> 16) & 1u)) >> 16;  // RNE
  return (u16)r;
}

DEVI uint32_t pk2bf(float a, float b) {  // low = a, high = b (RNE)
  return (uint32_t)f2bf(a) | ((uint32_t)f2bf(b) << 16);
}

DEVI void gload_lds16(const void* g, void* l) {
  __builtin_amdgcn_global_load_lds(
      (const __attribute__((address_space(1))) void*)g,
      (__attribute__((address_space(3))) void*)l, 16, 0, 0);
}

DEVI f32x4 mfma16(bf16x8 a, bf16x8 b, f32x4 c) {
  return __builtin_amdgcn_mfma_f32_16x16x32_bf16(a, b, c, 0, 0, 0);
}
DEVI f32x16 mfma32(bf16x8 a, bf16x8 b, f32x16 c) {
  return __builtin_amdgcn_mfma_f32_32x32x16_bf16(a, b, c, 0, 0, 0);
}

// XOR-swizzled u16 index into a [rows][64]-u16 LDS tile (16B-granular, T2/G4)
DEVI int swz16(int row, int c8) { return row * 64 + ((c8 ^ (row & 7)) << 3); }

// ---------------- prep: fold LoRA into Wk/Wv, cast weights + query to bf16 --
__global__ void prep_kernel(const float* __restrict__ query,
                            const float* __restrict__ W,
                            const float* __restrict__ ka, const float* __restrict__ kb,
                            const float* __restrict__ va, const float* __restrict__ vb,
                            const float* __restrict__ ow,
                            u16* __restrict__ Wm, u16* __restrict__ Wo,
                            u16* __restrict__ Aq) {
  const int W3 = 3 * DM * DM;
  const int WO = DM * DM;
  const int AQ = MROWS * DM;
  const int total = W3 + WO + AQ;
  for (int idx = blockIdx.x * blockDim.x + threadIdx.x; idx < total;
       idx += gridDim.x * blockDim.x) {
    if (idx < W3) {
      const int n = idx >> 10, k = idx & 1023;
      float w = W[idx];
      if (n >= 2 * DM) {
        const int n2 = n - 2 * DM;
        float a = 0.f;
#pragma unroll
        for (int r = 0; r < 16; ++r) a += va[r * DM + k] * vb[r * DM + n2];
        w += LORA_S * a;
      } else if (n >= DM) {
        const int n2 = n - DM;
        float a = 0.f;
#pragma unroll
        for (int r = 0; r < 16; ++r) a += ka[r * DM + k] * kb[r * DM + n2];
        w += LORA_S * a;
      }
      Wm[idx] = f2bf(w);
    } else if (idx < W3 + WO) {
      const int i = idx - W3;
      Wo[i] = f2bf(ow[i]);
    } else {
      const int i = idx - W3 - WO;
      Aq[i] = f2bf(query[i]);
    }
  }
}

// ---------------- GEMM: C[m][n] = sum_k A[m][k]*Bt[n][k] + bias[n] ----------
// 2-phase double-buffered (T3 minimum recipe): stage(k+1) issued BEFORE
// compute(k); single vmcnt(0)+barrier per K-step.
// EPIL 0: scatter q/k (coalesced-ish) and V via LDS-transpose (coalesced 16B).
// EPIL 1: fp32 C.
template <int EPIL>
__global__ __launch_bounds__(256) void gemm_bt(
    const u16* __restrict__ A, const u16* __restrict__ Bt,
    const float* __restrict__ bias, float* __restrict__ Cf,
    u16* __restrict__ Qb, u16* __restrict__ Kb, u16* __restrict__ Vt,
    int M, int N, int K) {
  constexpr int BM = 128, BN = 128, BK = 64;
  __shared__ alignas(16) u16 SM[2][(BM + BN) * BK];  // 64 KB double-buffer
  const int tid = threadIdx.x;
  const int wv = tid >> 6, ln = tid & 63;
  const int l16 = ln & 15, lhi = ln >> 4;
  const int row0 = blockIdx.x * BM, col0 = blockIdx.y * BN;
  const int wr = (wv >> 1) * 64, wc = (wv & 1) * 64;

  f32x4 acc[4][4];
#pragma unroll
  for (int i = 0; i < 4; ++i)
#pragma unroll
    for (int j = 0; j < 4; ++j) acc[i][j] = f32x4{0.f, 0.f, 0.f, 0.f};

  const int srow = ln >> 3;
  const int scol = (((ln & 7) ^ (ln >> 3)) & 7) * 8;

  auto stage = [&](int buf, int ks) {
    const int k0 = ks * BK;
    u16* Al = SM[buf];
    u16* Bl = SM[buf] + BM * BK;
#pragma unroll
    for (int it = 0; it < 4; ++it) {
      const int c = wv * 4 + it;  // 0..15, 8 rows each
      gload_lds16(A + (size_t)(row0 + c * 8 + srow) * K + k0 + scol, &Al[c * 512]);
      gload_lds16(Bt + (size_t)(col0 + c * 8 + srow) * K + k0 + scol, &Bl[c * 512]);
    }
  };

  const int NS = K / BK;
  stage(0, 0);
  __syncthreads();
  int cur = 0;
  for (int t = 0; t < NS; ++t) {
    if (t + 1 < NS) stage(cur ^ 1, t + 1);  // loads fly under the MFMAs
    const u16* Al = SM[cur];
    const u16* Bl = SM[cur] + BM * BK;
#pragma unroll
    for (int ks = 0; ks < 2; ++ks) {
      bf16x8 af[4], bfr[4];
#pragma unroll
      for (int m = 0; m < 4; ++m)
        af[m] = *(const bf16x8*)&Al[swz16(wr + m * 16 + l16, ks * 4 + lhi)];
#pragma unroll
      for (int n = 0; n < 4; ++n)
        bfr[n] = *(const bf16x8*)&Bl[swz16(wc + n * 16 + l16, ks * 4 + lhi)];
#pragma unroll
      for (int m = 0; m < 4; ++m)
#pragma unroll
        for (int n = 0; n < 4; ++n) acc[m][n] = mfma16(af[m], bfr[n], acc[m][n]);
    }
    __syncthreads();  // drains vmcnt(0): buf^1 staged & LDS reads done
    cur ^= 1;
  }

  if constexpr (EPIL == 0) {
    if (col0 >= 2 * DM) {
      // ---- V block: transpose 128x128 tile through LDS, coalesced stores
      u16* Cl = SM[0];  // all waves past final barrier; LDS free
#pragma unroll
      for (int m = 0; m < 4; ++m)
#pragma unroll
        for (int n = 0; n < 4; ++n) {
          const int lc = wc + n * 16 + l16;
          const float bc = bias[col0 + lc];
#pragma unroll
          for (int r = 0; r < 4; ++r) {
            const int rl = wr + m * 16 + lhi * 4 + r;
            const int tl = rl >> 1, bb = rl & 1;
            Cl[lc * 128 + bb * 64 + (((tl >> 3) ^ (lc & 7)) << 3) + (tl & 7)] =
                f2bf(acc[m][n][r] + bc);
          }
        }
      __syncthreads();
      const int h0 = (col0 - 2 * DM) >> 6;
      const int t0 = row0 >> 1;
#pragma unroll
      for (int i = 0; i < 8; ++i) {
        const int cid = i * 256 + tid;  // 2048 chunks of 8 u16
        const int lc = cid >> 4, bb = (cid >> 3) & 1, tc = cid & 7;
        bf16x8 ch = *(const bf16x8*)&Cl[lc * 128 + bb * 64 + ((tc ^ (lc & 7)) << 3)];
        const int h = h0 + (lc >> 6), dd = lc & 63;
        *(bf16x8*)&Vt[(((size_t)(bb * NH + h)) * HD + dd) * T_LEN + t0 + tc * 8] = ch;
      }
      return;
    }
  }

#pragma unroll
  for (int m = 0; m < 4; ++m) {
#pragma unroll
    for (int n = 0; n < 4; ++n) {
      const int col = col0 + wc + n * 16 + l16;
      const float bc = bias[col];
#pragma unroll
      for (int r = 0; r < 4; ++r) {
        const int row = row0 + wr + m * 16 + lhi * 4 + r;
        const float v = acc[m][n][r] + bc;
        if constexpr (EPIL == 0) {
          const int t = row >> 1, b = row & 1;  // row = t*BSZ + b
          if (col < DM) {
            const int h = col >> 6, dd = col & 63;
            Qb[(((size_t)(b * NH + h)) * T_LEN + t) * HD + dd] = f2bf(v * QSCALE);
          } else {
            const int c2 = col - DM, h = c2 >> 6, dd = c2 & 63;
            Kb[(((size_t)(b * NH + h)) * T_LEN + t) * HD + dd] = f2bf(v);
          }
        } else {
          Cf[(size_t)row * N + col] = v;
        }
      }
    }
  }
}

// ---------------- flash attention: swapped-QK^T, in-register softmax --------
// 4 waves x 32 q-rows; KV tiles of 64 double-buffered; 32x32x16 MFMA.
// Per wave: S^T = K*Q'^T (lane owns one q column), softmax in-register,
// P->bf16 via cvt_pk + permlane32_swap, O^T = V^T * P^T.
__global__ __launch_bounds__(256) void attn_kernel(const u16* __restrict__ Qb,
                                                   const u16* __restrict__ Kb,
                                                   const u16* __restrict__ Vt,
                                                   u16* __restrict__ Ob) {
  constexpr int KBLK = 64;
  constexpr int NT = T_LEN / KBLK;  // 32
  __shared__ alignas(16) u16 Kl[2][KBLK * HD];   // [key][d]
  __shared__ alignas(16) u16 Vl[2][HD * KBLK];   // [dim][key]

  const int tid = threadIdx.x;
  const int wv = tid >> 6, ln = tid & 63;
  const int l32 = ln & 31, hi = ln >> 5;
  const int bh = blockIdx.y;
  const int b = bh >> 4, h = bh & 15;
  const int q0 = blockIdx.x * 128 + wv * 32;  // t-index base of this wave

  const u16* Qh = Qb + (size_t)bh * T_LEN * HD;
  const u16* Kh = Kb + (size_t)bh * T_LEN * HD;
  const u16* Vh = Vt + (size_t)bh * HD * T_LEN;

  // Q B-fragments: row = q = l32, k = kd*16 + hi*8 + j  (pre-scaled by QSCALE)
  bf16x8 qf[4];
#pragma unroll
  for (int kd = 0; kd < 4; ++kd)
    qf[kd] = *(const bf16x8*)&Qh[(size_t)(q0 + l32) * HD + kd * 16 + hi * 8];

  f32x16 ot[2] = {f32x16{}, f32x16{}};  // O^T accumulators (dim tiles 0,1)
  float mi = -1e30f, li = 0.f;

  const int srow = ln >> 3;
  const int scol = (((ln & 7) ^ (ln >> 3)) & 7) * 8;

  auto stage = [&](int buf, int kt) {
    const int kt0 = kt * KBLK;
#pragma unroll
    for (int it = 0; it < 2; ++it) {
      const int c = wv * 2 + it;  // 0..7
      gload_lds16(Kh + (size_t)(kt0 + c * 8 + srow) * HD + scol, &Kl[buf][c * 512]);
      gload_lds16(Vh + (size_t)(c * 8 + srow) * T_LEN + kt0 + scol, &Vl[buf][c * 512]);
    }
  };

  stage(0, 0);
  __syncthreads();
  int cur = 0;
  for (int kt = 0; kt < NT; ++kt) {
    if (kt + 1 < NT) stage(cur ^ 1, kt + 1);

    // S^T[key][q]: st[mk], key = mk*32 + (r&3) + 8*(r>>2) + 4*hi, q col = l32
    f32x16 st[2] = {f32x16{}, f32x16{}};
#pragma unroll
    for (int kd = 0; kd < 4; ++kd) {
      bf16x8 k0 = *(const bf16x8*)&Kl[cur][swz16(l32, kd * 2 + hi)];
      bf16x8 k1 = *(const bf16x8*)&Kl[cur][swz16(32 + l32, kd * 2 + hi)];
      st[0] = mfma32(k0, qf[kd], st[0]);
      st[1] = mfma32(k1, qf[kd], st[1]);
    }

    // tile max for this q column (in-lane 32 values + partner lane)
    float tm = st[0][0];
#pragma unroll
    for (int r = 1; r < 16; ++r) tm = fmaxf(tm, st[0][r]);
#pragma unroll
    for (int r = 0; r < 16; ++r) tm = fmaxf(tm, st[1][r]);
    tm = fmaxf(tm, __shfl_xor(tm, 32));

    // defer-max (T13, THR=8 in exp2 domain): rescale only on real growth
    if (!__all(tm <= mi + 8.0f)) {
      const float mn = fmaxf(mi, tm);
      const float al = __builtin_amdgcn_exp2f(mi - mn);
      li *= al;
#pragma unroll
      for (int dt = 0; dt < 2; ++dt)
#pragma unroll
        for (int r = 0; r < 16; ++r) ot[dt][r] *= al;
      mi = mn;
    }

    // P = exp2(S^T - mi), packed to bf16 pairs; row-sum accumulated
    float ts = 0.f;
    uint32_t c[2][8];
#pragma unroll
    for (int mk = 0; mk < 2; ++mk)
#pragma unroll
      for (int d = 0; d < 8; ++d) {
        const float pa = __builtin_amdgcn_exp2f(st[mk][2 * d] - mi);
        const float pb = __builtin_amdgcn_exp2f(st[mk][2 * d + 1] - mi);
        ts += pa + pb;
        c[mk][d] = pk2bf(pa, pb);
      }
    ts += __shfl_xor(ts, 32);
    li += ts;

    // O^T += V^T P^T : redistribute P quads via permlane32_swap -> B-frags
#pragma unroll
    for (int ksl = 0; ksl < 4; ++ksl) {
      const int mk = ksl >> 1, s2 = ksl & 1;
      uint32_t a0 = c[mk][4 * s2 + 0], b0 = c[mk][4 * s2 + 2];
      uint32_t a1 = c[mk][4 * s2 + 1], b1 = c[mk][4 * s2 + 3];
      u32x2 r0 = __builtin_amdgcn_permlane32_swap(a0, b0, false, false);
      u32x2 r1 = __builtin_amdgcn_permlane32_swap(a1, b1, false, false);
      union { bf16x8 v; uint32_t u[4]; } pu;
      pu.u[0] = r0[0]; pu.u[1] = r1[0]; pu.u[2] = r0[1]; pu.u[3] = r1[1];
      bf16x8 vf0 = *(const bf16x8*)&Vl[cur][swz16(l32, ksl * 2 + hi)];
      bf16x8 vf1 = *(const bf16x8*)&Vl[cur][swz16(32 + l32, ksl * 2 + hi)];
      ot[0] = mfma32(vf0, pu.v, ot[0]);
      ot[1] = mfma32(vf1, pu.v, ot[1]);
    }
    __syncthreads();
    cur ^= 1;
  }

  // epilogue: O^T[dim][q]/li -> Ob[(t*BSZ+b)*DM + h*64 + dim], 4-dim packed
  const float inv = 1.0f / li;
  const size_t rowbase = ((size_t)(q0 + l32) * BSZ + b) * DM + h * HD;
#pragma unroll
  for (int dt = 0; dt < 2; ++dt) {
#pragma unroll
    for (int g = 0; g < 4; ++g) {
      const float v0 = ot[dt][4 * g + 0] * inv;
      const float v1 = ot[dt][4 * g + 1] * inv;
      const float v2 = ot[dt][4 * g + 2] * inv;
      const float v3 = ot[dt][4 * g + 3] * inv;
      u32x2 w; w[0] = pk2bf(v0, v1); w[1] = pk2bf(v2, v3);
      const int dim = dt * 32 + 8 * g + 4 * hi;
      *(u32x2*)&Ob[rowbase + dim] = w;
    }
  }
}

// ---------------- launcher --------------------------------------------------
extern "C" void kernel_launch(void* const* d_in, const int* in_sizes, int n_in,
                              void* d_out, int out_size, void* d_ws, size_t ws_size,
                              hipStream_t stream) {
  const float* query = (const float*)d_in[0];
  const float* W     = (const float*)d_in[5];
  const float* bias  = (const float*)d_in[6];
  const float* ow    = (const float*)d_in[7];
  const float* ob    = (const float*)d_in[8];
  const float* ka    = (const float*)d_in[9];
  const float* kb    = (const float*)d_in[10];
  const float* va    = (const float*)d_in[11];
  const float* vb    = (const float*)d_in[12];

  char* ws = (char*)d_ws;
  u16* Wm = (u16*)ws; ws += (size_t)3 * DM * DM * 2;       // 6 MB
  u16* Wo = (u16*)ws; ws += (size_t)DM * DM * 2;           // 2 MB
  u16* Aq = (u16*)ws; ws += (size_t)MROWS * DM * 2;        // 8 MB
  u16* Qb = (u16*)ws; ws += (size_t)BSZ * NH * T_LEN * HD * 2;  // 8 MB
  u16* Kb = (u16*)ws; ws += (size_t)BSZ * NH * T_LEN * HD * 2;  // 8 MB
  u16* Vt = (u16*)ws; ws += (size_t)BSZ * NH * T_LEN * HD * 2;  // 8 MB
  u16* Ob = (u16*)ws; ws += (size_t)MROWS * DM * 2;        // 8 MB

  prep_kernel<<<2048, 256, 0, stream>>>(query, W, ka, kb, va, vb, ow, Wm, Wo, Aq);

  gemm_bt<0><<<dim3(MROWS / 128, (3 * DM) / 128), 256, 0, stream>>>(
      Aq, Wm, bias, nullptr, Qb, Kb, Vt, MROWS, 3 * DM, DM);

  attn_kernel<<<dim3(T_LEN / 128, BSZ * NH), 256, 0, stream>>>(Qb, Kb, Vt, Ob);

  gemm_bt<1><<<dim3(MROWS / 128, DM / 128), 256, 0, stream>>>(
      Ob, Wo, ob, (float*)d_out, nullptr, nullptr, nullptr, MROWS, DM, DM);
}